// Round 13
// baseline (429.114 us; speedup 1.0000x reference)
//
#include <hip/hip_runtime.h>

typedef __attribute__((ext_vector_type(8))) short short8;
typedef __attribute__((ext_vector_type(4))) float floatx4;
typedef __attribute__((ext_vector_type(8))) _Float16 half8;

// ---- bf16 split helpers (round-to-nearest-even) ----
static __device__ __forceinline__ unsigned short f2bf(float f) {
    unsigned u = __float_as_uint(f);
    u += 0x7fff + ((u >> 16) & 1);
    return (unsigned short)(u >> 16);
}

// exact split of an fp16-origin fp32 value into bf16 hi + bf16 lo (truncation, lossless)
static __device__ __forceinline__ void split_h8(half8 a, short8& ah, short8& al) {
    #pragma unroll
    for (int j = 0; j < 8; ++j) {
        float fv = (float)a[j];
        unsigned u = __float_as_uint(fv);
        float lo = fv - __uint_as_float(u & 0xFFFF0000u);
        ah[j] = (short)(u >> 16);
        al[j] = (short)(__float_as_uint(lo) >> 16);
    }
}

// ---------------- CSR build (degi memset to 0 by host-side hipMemsetAsync) ----------------
// Weight-free CSR (R8): w(r,c)=dinv[r]*dinv[c] factored into gemm epilogue (dinv[r]) and
// agg epilogue (dinv[c]). csr entry = 4-byte source index. Self-loops not stored.

__global__ void count_kernel(const int* __restrict__ ei, int* degi, int E) {
    int e = blockIdx.x * 256 + threadIdx.x;
    if (e < E) atomicAdd(&degi[ei[E + e]], 1);   // col = dest
}

__global__ __launch_bounds__(256) void scan_bsum_kernel(const int* __restrict__ degi,
                                                        float* __restrict__ dinv,
                                                        int* bsum, int n) {
    int tid = threadIdx.x;
    int i = blockIdx.x * 256 + tid;
    int d = (i < n) ? degi[i] : 0;
    if (i < n) dinv[i] = rsqrtf((float)(d + 1));  // +1 self-loop for normalization
    int v = d;                                    // offsets count only real edges
    #pragma unroll
    for (int off = 32; off > 0; off >>= 1) v += __shfl_down(v, off);
    __shared__ int ws[4];
    if ((tid & 63) == 0) ws[tid >> 6] = v;
    __syncthreads();
    if (tid == 0) bsum[blockIdx.x] = ws[0] + ws[1] + ws[2] + ws[3];
}

__global__ __launch_bounds__(256) void scan_emit_kernel(const int* __restrict__ degi,
                                                        const int* __restrict__ bsum,
                                                        int* rp, int* cursor, int n, int nb) {
    int tid = threadIdx.x;
    int bid = blockIdx.x;
    int contrib = 0;
    for (int t = tid; t < bid; t += 256) contrib += bsum[t];
    int cr = contrib;
    #pragma unroll
    for (int off = 32; off > 0; off >>= 1) cr += __shfl_down(cr, off);
    __shared__ int wr[4];
    __shared__ int s_boff;
    if ((tid & 63) == 0) wr[tid >> 6] = cr;
    __syncthreads();
    if (tid == 0) s_boff = wr[0] + wr[1] + wr[2] + wr[3];
    __syncthreads();

    int i = bid * 256 + tid;
    int v = (i < n) ? degi[i] : 0;
    int lane = tid & 63, wid = tid >> 6;
    int x = v;
    #pragma unroll
    for (int off = 1; off < 64; off <<= 1) {
        int y = __shfl_up(x, off);
        if (lane >= off) x += y;
    }
    __shared__ int ws[4];
    if (lane == 63) ws[wid] = x;
    __syncthreads();
    if (tid == 0) { int a = 0; for (int j = 0; j < 4; ++j) { int t = ws[j]; ws[j] = a; a += t; } }
    __syncthreads();
    int excl = x - v + ws[wid] + s_boff;
    if (i < n) { rp[i] = excl; cursor[i] = excl; }
    if (i == n - 1) rp[n] = excl + v;
}

__global__ void fill_kernel(const int* __restrict__ ei, int* cursor,
                            int* __restrict__ csr, int E) {
    int e = blockIdx.x * 256 + threadIdx.x;
    if (e >= E) return;
    int r = ei[e], c = ei[E + e];
    int pos = atomicAdd(&cursor[c], 1);
    csr[pos] = r;
}

// ---------------- weight packing: W[k][n] -> Wt16[n][k] fp16 ----------------

__global__ void packw_kernel(const float* w0, const float* w1, const float* w2,
                             const float* w3, const float* w4, const float* w5,
                             _Float16* __restrict__ wt) {
    int l = blockIdx.y;
    const float* W = (l == 0) ? w0 : (l == 1) ? w1 : (l == 2) ? w2
                   : (l == 3) ? w3 : (l == 4) ? w4 : w5;
    int idx = blockIdx.x * 256 + threadIdx.x;
    int k = idx >> 7, nn = idx & 127;
    wt[l * 16384 + nn * 128 + k] = (_Float16)W[k * 128 + nn];
}

// ---------------- split-bf16 MFMA GEMM core ----------------
// A-input: fp16 chunk4 [4][node][32] (R9 layout). W: fp16 in LDS (33 KB, stride 130),
// split to bf16 hi/lo IN REGISTERS (exact truncation). 3-MFMA product.
// 1024-thread blocks: waves w and w+8 share rows, compute complementary 4-ct halves
// -> 16 waves/block, 6256 waves total (2x R9's TLP). __launch_bounds__(1024,8)
// targets <=64 VGPR -> 2 blocks/CU = 32 waves/CU where co-resident.

#define W16_STRIDE 130

static __device__ __forceinline__ void stage_w16(const _Float16* __restrict__ Wt,
                                                 _Float16* Wlds, int tid, int nthr) {
    int pieces = 2048;                       // 128*128/8
    for (int c = tid; c < pieces; c += nthr) {
        int row = c >> 4, piece = c & 15;
        *(half8*)&Wlds[row * W16_STRIDE + piece * 8] =
            *(const half8*)(Wt + (size_t)row * 128 + piece * 8);
    }
}

__global__ __launch_bounds__(1024, 8) void gemm_kernel(const _Float16* __restrict__ A,
                                                       const _Float16* __restrict__ Wt,
                                                       const float* __restrict__ dinv,
                                                       void* __restrict__ C, int n, int outf) {
    __shared__ _Float16 Wlds[128 * W16_STRIDE];
    int tid = threadIdx.x;
    int wave = tid >> 6, lane = tid & 63;
    int cthalf = wave >> 3;                  // 0: ct 0-3, 1: ct 4-7
    int wrow = wave & 7;                     // row-group
    int m = lane & 15, quad = lane >> 4;
    int row0 = blockIdx.x * 128 + wrow * 16;
    int arow = row0 + m; if (arow > n - 1) arow = n - 1;
    size_t n32 = (size_t)n * 32;
    const _Float16* abase = A + (size_t)arow * 32 + quad * 8;

    half8 pa[4];
    #pragma unroll
    for (int kc = 0; kc < 4; ++kc) pa[kc] = *(const half8*)(abase + (size_t)kc * n32);

    stage_w16(Wt, Wlds, tid, 1024);

    floatx4 acc[4];
    #pragma unroll
    for (int ci = 0; ci < 4; ++ci) acc[ci] = (floatx4){0.f, 0.f, 0.f, 0.f};
    __syncthreads();

    #pragma unroll
    for (int kc = 0; kc < 4; ++kc) {
        short8 ah, al;
        split_h8(pa[kc], ah, al);
        #pragma unroll
        for (int ci = 0; ci < 4; ++ci) {
            int ct = cthalf * 4 + ci;
            half8 w16 = *(const half8*)&Wlds[(ct * 16 + m) * W16_STRIDE + kc * 32 + quad * 8];
            short8 wh, wl;
            split_h8(w16, wh, wl);
            acc[ci] = __builtin_amdgcn_mfma_f32_16x16x32_bf16(ah, wl, acc[ci], 0, 0, 0);
            acc[ci] = __builtin_amdgcn_mfma_f32_16x16x32_bf16(al, wh, acc[ci], 0, 0, 0);
            acc[ci] = __builtin_amdgcn_mfma_f32_16x16x32_bf16(ah, wh, acc[ci], 0, 0, 0);
        }
    }

    float dv[4];
    #pragma unroll
    for (int r = 0; r < 4; ++r) dv[r] = dinv[min(row0 + quad * 4 + r, n - 1)];

    #pragma unroll
    for (int ci = 0; ci < 4; ++ci) {
        int ct = cthalf * 4 + ci;
        #pragma unroll
        for (int r = 0; r < 4; ++r) {
            int row = row0 + quad * 4 + r;
            if (row < n) {
                if (outf) {
                    ((float*)C)[(size_t)row * 128 + ct * 16 + m] = acc[ci][r];
                } else {
                    ((_Float16*)C)[(size_t)(ct >> 1) * n32 + (size_t)row * 32
                                   + (ct & 1) * 16 + m] = (_Float16)(acc[ci][r] * dv[r]);
                }
            }
        }
    }
}

// layer-0 variant: fp32 x row-major input, 512 threads (runs once; VGPR headroom for
// the fp32 prefetch), fp16-W LDS, chunk4 fp16 out (dinv-scaled)
__global__ __launch_bounds__(512, 4) void gemm0_kernel(const float* __restrict__ X,
                                                       const _Float16* __restrict__ Wt,
                                                       const float* __restrict__ dinv,
                                                       _Float16* __restrict__ C, int n) {
    __shared__ _Float16 Wlds[128 * W16_STRIDE];
    int tid = threadIdx.x;
    int wave = tid >> 6, lane = tid & 63;
    int m = lane & 15, quad = lane >> 4;
    int row0 = blockIdx.x * 128 + wave * 16;
    int arow = row0 + m; if (arow > n - 1) arow = n - 1;
    size_t n32 = (size_t)n * 32;
    const float* aptr = X + (size_t)arow * 128 + quad * 8;

    floatx4 pf0[4], pf1[4];
    #pragma unroll
    for (int kc = 0; kc < 4; ++kc) {
        pf0[kc] = *(const floatx4*)(aptr + kc * 32);
        pf1[kc] = *(const floatx4*)(aptr + kc * 32 + 4);
    }

    stage_w16(Wt, Wlds, tid, 512);

    floatx4 acc[8];
    #pragma unroll
    for (int ct = 0; ct < 8; ++ct) acc[ct] = (floatx4){0.f, 0.f, 0.f, 0.f};
    __syncthreads();

    #pragma unroll
    for (int kc = 0; kc < 4; ++kc) {
        short8 ah, al;
        #pragma unroll
        for (int j = 0; j < 8; ++j) {
            float fv = (j < 4) ? pf0[kc][j] : pf1[kc][j - 4];
            unsigned short h = f2bf(fv);
            ah[j] = (short)h;
            al[j] = (short)f2bf(fv - __uint_as_float((unsigned)h << 16));
        }
        #pragma unroll
        for (int ct = 0; ct < 8; ++ct) {
            half8 w16 = *(const half8*)&Wlds[(ct * 16 + m) * W16_STRIDE + kc * 32 + quad * 8];
            short8 wh, wl;
            split_h8(w16, wh, wl);
            acc[ct] = __builtin_amdgcn_mfma_f32_16x16x32_bf16(ah, wl, acc[ct], 0, 0, 0);
            acc[ct] = __builtin_amdgcn_mfma_f32_16x16x32_bf16(al, wh, acc[ct], 0, 0, 0);
            acc[ct] = __builtin_amdgcn_mfma_f32_16x16x32_bf16(ah, wh, acc[ct], 0, 0, 0);
        }
    }

    float dv[4];
    #pragma unroll
    for (int r = 0; r < 4; ++r) dv[r] = dinv[min(row0 + quad * 4 + r, n - 1)];

    #pragma unroll
    for (int ct = 0; ct < 8; ++ct) {
        #pragma unroll
        for (int r = 0; r < 4; ++r) {
            int row = row0 + quad * 4 + r;
            if (row < n)
                C[(size_t)(ct >> 1) * n32 + (size_t)row * 32 + (ct & 1) * 16 + m] =
                    (_Float16)(acc[ct][r] * dv[r]);
        }
    }
}

// ---------------- aggregation: R9 chunked (proven best), fp16 in/out ----------------
// t layout: [4][node][32] fp16 (dinv-prescaled). blockIdx%8 = s: chunk=s&3, half=s>>2.
// out h[c] = relu( dinv[c] * (t[c] + sum t[r]) + bias ), fp16 chunk4.

__global__ __launch_bounds__(256) void agg_kernel(const _Float16* __restrict__ t,
                                                  const float* __restrict__ bias,
                                                  const int* __restrict__ rp,
                                                  const int* __restrict__ csr,
                                                  const float* __restrict__ dinv,
                                                  _Float16* __restrict__ outp, int n, int nh) {
    int s = blockIdx.x & 7;
    int chunk = s & 3;
    int half = s >> 2;
    int nb = blockIdx.x >> 3;
    int group = threadIdx.x >> 2;          // 64 nodes per block
    int lane4 = threadIdx.x & 3;
    int j = half * nh + nb * 64 + group;
    int jend = half ? n : nh;
    if (j >= jend) return;
    size_t n32 = (size_t)n * 32;
    const _Float16* tc = t + (size_t)chunk * n32;
    int c8 = lane4 * 8;
    int p0 = rp[j], p1 = rp[j + 1];

    float dj = dinv[j];
    half8 vs = *(const half8*)&tc[(size_t)j * 32 + c8];

    float acc[8];
    #pragma unroll
    for (int k = 0; k < 8; ++k) acc[k] = (float)vs[k];

    int p = p0;
    for (; p + 8 <= p1; p += 8) {
        int e[8];
        #pragma unroll
        for (int i = 0; i < 8; ++i) e[i] = csr[p + i];
        half8 v[8];
        #pragma unroll
        for (int i = 0; i < 8; ++i)
            v[i] = *(const half8*)&tc[(size_t)e[i] * 32 + c8];
        #pragma unroll
        for (int i = 0; i < 8; ++i) {
            #pragma unroll
            for (int k = 0; k < 8; ++k) acc[k] += (float)v[i][k];
        }
    }
    if (p < p1) {
        int lim = p1 - 1;
        int e[8];
        #pragma unroll
        for (int i = 0; i < 8; ++i) e[i] = csr[min(p + i, lim)];
        float msk[8];
        #pragma unroll
        for (int i = 0; i < 8; ++i) msk[i] = (p + i < p1) ? 1.f : 0.f;
        half8 v[8];
        #pragma unroll
        for (int i = 0; i < 8; ++i)
            v[i] = *(const half8*)&tc[(size_t)e[i] * 32 + c8];
        #pragma unroll
        for (int i = 0; i < 8; ++i) {
            #pragma unroll
            for (int k = 0; k < 8; ++k) acc[k] += msk[i] * (float)v[i][k];
        }
    }

    int cbase = chunk * 32 + c8;
    float4 b0 = *(const float4*)&bias[cbase];
    float4 b1 = *(const float4*)&bias[cbase + 4];
    float bb[8] = {b0.x, b0.y, b0.z, b0.w, b1.x, b1.y, b1.z, b1.w};
    half8 hv;
    #pragma unroll
    for (int k = 0; k < 8; ++k) hv[k] = (_Float16)fmaxf(fmaf(dj, acc[k], bb[k]), 0.f);

    *(half8*)&outp[(size_t)chunk * n32 + (size_t)j * 32 + c8] = hv;
}

// ---------------- pooling + classifier (row-major fp32 final activations) ----------------

__global__ __launch_bounds__(256) void pool_kernel(const float* __restrict__ t,
                                                   const float* __restrict__ bfc,
                                                   const int* __restrict__ batch,
                                                   const float* __restrict__ Wlin,
                                                   const float* __restrict__ blin,
                                                   float* __restrict__ out, int n) {
    int g = blockIdx.x;
    int tid = threadIdx.x;
    int lo = 0, hi = n;
    while (lo < hi) { int m = (lo + hi) >> 1; if (batch[m] < g) lo = m + 1; else hi = m; }
    int start = lo;
    lo = start; hi = n;
    while (lo < hi) { int m = (lo + hi) >> 1; if (batch[m] < g + 1) lo = m + 1; else hi = m; }
    int end = lo;

    int lane = tid & 31, sub = tid >> 5;
    int c4 = lane * 4;
    float4 bv = *(const float4*)&bfc[c4];
    float sx = 0.f, sy = 0.f, sz = 0.f, sw = 0.f;
    for (int j = start + sub; j < end; j += 8) {
        float4 v = *(const float4*)&t[(size_t)j * 128 + c4];
        sx += fmaxf(v.x + bv.x, 0.f);
        sy += fmaxf(v.y + bv.y, 0.f);
        sz += fmaxf(v.z + bv.z, 0.f);
        sw += fmaxf(v.w + bv.w, 0.f);
    }
    __shared__ float red[8][128];
    red[sub][c4] = sx; red[sub][c4 + 1] = sy; red[sub][c4 + 2] = sz; red[sub][c4 + 3] = sw;
    __syncthreads();
    __shared__ float pooled[128];
    if (tid < 128) {
        float s = 0.f;
        #pragma unroll
        for (int k = 0; k < 8; ++k) s += red[k][tid];
        float pv = s / fmaxf((float)(end - start), 1.f);
        pooled[tid] = pv;
        out[1280 + g * 128 + tid] = pv;
    }
    __syncthreads();
    if (tid < 10) {
        float a = blin[tid];
        for (int k = 0; k < 128; ++k) a += pooled[k] * Wlin[k * 10 + tid];
        out[g * 10 + tid] = a;
    }
}

// ---------------- launch ----------------

extern "C" void kernel_launch(void* const* d_in, const int* in_sizes, int n_in,
                              void* d_out, int out_size, void* d_ws, size_t ws_size,
                              hipStream_t stream) {
    const float* x     = (const float*)d_in[0];
    const int*   ei    = (const int*)d_in[1];
    const int*   batch = (const int*)d_in[2];
    const float* Wl[6] = {(const float*)d_in[3], (const float*)d_in[5], (const float*)d_in[7],
                          (const float*)d_in[9], (const float*)d_in[11], (const float*)d_in[13]};
    const float* bl[6] = {(const float*)d_in[4], (const float*)d_in[6], (const float*)d_in[8],
                          (const float*)d_in[10], (const float*)d_in[12], (const float*)d_in[14]};
    const float* Wlin = (const float*)d_in[15];
    const float* blin = (const float*)d_in[16];

    const int N = in_sizes[2];        // 50000
    const int E = in_sizes[1] / 2;    // 600000
    (void)n_in; (void)out_size; (void)ws_size;

    char* p = (char*)d_ws;
    auto carve = [&](size_t bytes) { void* r = (void*)p; p += (bytes + 255) & ~(size_t)255; return r; };
    _Float16*       tA     = (_Float16*)carve((size_t)N * 128 * 2);   // gemm out (dinv-scaled)
    _Float16*       tB     = (_Float16*)carve((size_t)N * 128 * 2);   // agg out (h)
    float*          tf     = (float*)carve((size_t)N * 128 * 4);      // final fp32 activations
    int*            degi   = (int*)carve((size_t)N * 4);
    float*          dinv   = (float*)carve((size_t)N * 4);
    int*            rp     = (int*)carve((size_t)(N + 1) * 4);
    int*            cursor = (int*)carve((size_t)N * 4);
    int*            csr    = (int*)carve((size_t)E * 4);              // 4B source index only
    int*            bsum   = (int*)carve(256 * 4);
    _Float16*       wt16   = (_Float16*)carve(6 * 16384 * 2);         // fp16 W^T per layer

    int gN = (N + 255) / 256;
    hipMemsetAsync(degi, 0, (size_t)N * 4, stream);
    count_kernel<<<(E + 255) / 256, 256, 0, stream>>>(ei, degi, E);
    scan_bsum_kernel<<<gN, 256, 0, stream>>>(degi, dinv, bsum, N);
    scan_emit_kernel<<<gN, 256, 0, stream>>>(degi, bsum, rp, cursor, N, gN);
    fill_kernel<<<(E + 255) / 256, 256, 0, stream>>>(ei, cursor, csr, E);
    packw_kernel<<<dim3(64, 6), 256, 0, stream>>>(Wl[0], Wl[1], Wl[2], Wl[3], Wl[4], Wl[5],
                                                  wt16);

    int NH = (N + 1) / 2;
    int gGemm = (N + 127) / 128;
    int gAgg  = 8 * ((NH + 63) / 64);
    gemm0_kernel<<<gGemm, 512, 0, stream>>>(x, wt16, dinv, tA, N);
    agg_kernel<<<gAgg, 256, 0, stream>>>(tA, bl[0], rp, csr, dinv, tB, N, NH);
    for (int l = 1; l < 5; ++l) {
        gemm_kernel<<<gGemm, 1024, 0, stream>>>(tB, wt16 + l * 16384, dinv,
                                                (void*)tA, N, 0);
        agg_kernel<<<gAgg, 256, 0, stream>>>(tA, bl[l], rp, csr, dinv, tB, N, NH);
    }
    gemm_kernel<<<gGemm, 1024, 0, stream>>>(tB, wt16 + 5 * 16384, dinv,
                                            (void*)tf, N, 1);
    pool_kernel<<<128, 256, 0, stream>>>(tf, bl[5], batch, Wlin, blin, (float*)d_out, N);
}

// Round 14
// 393.440 us; speedup vs baseline: 1.0907x; 1.0907x over previous
//
#include <hip/hip_runtime.h>

typedef __attribute__((ext_vector_type(8))) short short8;
typedef __attribute__((ext_vector_type(4))) float floatx4;
typedef __attribute__((ext_vector_type(8))) _Float16 half8;

// ---- bf16 split helpers (round-to-nearest-even) ----
static __device__ __forceinline__ unsigned short f2bf(float f) {
    unsigned u = __float_as_uint(f);
    u += 0x7fff + ((u >> 16) & 1);
    return (unsigned short)(u >> 16);
}
static __device__ __forceinline__ float bf2f(unsigned short h) {
    return __uint_as_float((unsigned)h << 16);
}

// ---------------- fused count + weight-pack ----------------
// blocks [0, gCount): degree count (atomicAdd on dest).
// blocks [gCount, gCount+384): pack W[k][n] -> Wt_hi[n][k], Wt_lo[n][k] (6 layers x 64).
// Independent work, disjoint block ranges -> one dispatch boundary saved.

__global__ void count_packw_kernel(const int* __restrict__ ei, int* degi, int E, int gCount,
                                   const float* w0, const float* w1, const float* w2,
                                   const float* w3, const float* w4, const float* w5,
                                   unsigned short* __restrict__ hi,
                                   unsigned short* __restrict__ lo) {
    int bid = blockIdx.x;
    if (bid < gCount) {
        int e = bid * 256 + threadIdx.x;
        if (e < E) atomicAdd(&degi[ei[E + e]], 1);   // col = dest
    } else {
        int pb = bid - gCount;
        int l = pb >> 6;
        const float* W = (l == 0) ? w0 : (l == 1) ? w1 : (l == 2) ? w2
                       : (l == 3) ? w3 : (l == 4) ? w4 : w5;
        int idx = (pb & 63) * 256 + threadIdx.x;
        int k = idx >> 7, nn = idx & 127;
        float v = W[k * 128 + nn];
        unsigned short h = f2bf(v);
        unsigned short ls = f2bf(v - bf2f(h));
        hi[l * 16384 + nn * 128 + k] = h;
        lo[l * 16384 + nn * 128 + k] = ls;
    }
}

// ---------------- CSR build (degi memset to 0 by host-side hipMemsetAsync) ----------------
// Weight-free CSR (R8): w(r,c)=dinv[r]*dinv[c] factored into gemm epilogue (dinv[r]) and
// agg epilogue (dinv[c]). csr entry = 4-byte source index. Self-loops not stored.

__global__ __launch_bounds__(256) void scan_bsum_kernel(const int* __restrict__ degi,
                                                        float* __restrict__ dinv,
                                                        int* bsum, int n) {
    int tid = threadIdx.x;
    int i = blockIdx.x * 256 + tid;
    int d = (i < n) ? degi[i] : 0;
    if (i < n) dinv[i] = rsqrtf((float)(d + 1));  // +1 self-loop for normalization
    int v = d;                                    // offsets count only real edges
    #pragma unroll
    for (int off = 32; off > 0; off >>= 1) v += __shfl_down(v, off);
    __shared__ int ws[4];
    if ((tid & 63) == 0) ws[tid >> 6] = v;
    __syncthreads();
    if (tid == 0) bsum[blockIdx.x] = ws[0] + ws[1] + ws[2] + ws[3];
}

__global__ __launch_bounds__(256) void scan_emit_kernel(const int* __restrict__ degi,
                                                        const int* __restrict__ bsum,
                                                        int* rp, int* cursor, int n, int nb) {
    int tid = threadIdx.x;
    int bid = blockIdx.x;
    int contrib = 0;
    for (int t = tid; t < bid; t += 256) contrib += bsum[t];
    int cr = contrib;
    #pragma unroll
    for (int off = 32; off > 0; off >>= 1) cr += __shfl_down(cr, off);
    __shared__ int wr[4];
    __shared__ int s_boff;
    if ((tid & 63) == 0) wr[tid >> 6] = cr;
    __syncthreads();
    if (tid == 0) s_boff = wr[0] + wr[1] + wr[2] + wr[3];
    __syncthreads();

    int i = bid * 256 + tid;
    int v = (i < n) ? degi[i] : 0;
    int lane = tid & 63, wid = tid >> 6;
    int x = v;
    #pragma unroll
    for (int off = 1; off < 64; off <<= 1) {
        int y = __shfl_up(x, off);
        if (lane >= off) x += y;
    }
    __shared__ int ws[4];
    if (lane == 63) ws[wid] = x;
    __syncthreads();
    if (tid == 0) { int a = 0; for (int j = 0; j < 4; ++j) { int t = ws[j]; ws[j] = a; a += t; } }
    __syncthreads();
    int excl = x - v + ws[wid] + s_boff;
    if (i < n) { rp[i] = excl; cursor[i] = excl; }
    if (i == n - 1) rp[n] = excl + v;
}

__global__ void fill_kernel(const int* __restrict__ ei, int* cursor,
                            int* __restrict__ csr, int E) {
    int e = blockIdx.x * 256 + threadIdx.x;
    if (e >= E) return;
    int r = ei[e], c = ei[E + e];
    int pos = atomicAdd(&cursor[c], 1);
    csr[pos] = r;
}

// ---------------- split-bf16 MFMA GEMM core (R9, best measured) ----------------
// A-input: fp16 chunk4 [4][node][32] (the ONE unified activation format).
// Exact in-register truncation split: fp16 value = ah(bf16) + al(bf16) LOSSLESSLY.
// outf=0: store t'[row] = dinv[row]*acc as fp16 chunk4 (gather operand).
// outf=1: fp32 row-major (final layer, feeds pool).
// 3-MFMA split product (ah*wh + al*wh + ah*wl; al*wl ~2^-19, dropped).

#define WLDS_STRIDE 260

static __device__ __forceinline__ void stage_w(const unsigned short* __restrict__ Wth,
                                               const unsigned short* __restrict__ Wtl,
                                               unsigned short* Wlds, int tid) {
    #pragma unroll
    for (int it = 0; it < 8; ++it) {
        int c = it * 512 + tid;
        int row = c >> 5, piece = c & 31;
        const unsigned short* src = (piece < 16)
            ? (Wth + (size_t)row * 128 + piece * 8)
            : (Wtl + (size_t)row * 128 + (piece - 16) * 8);
        int dst = row * WLDS_STRIDE + ((piece < 16) ? piece * 8 : 128 + (piece - 16) * 8);
        *(short8*)&Wlds[dst] = *(const short8*)src;
    }
}

// exact split of an fp16-origin fp32 value into bf16 hi + bf16 lo (truncation, lossless)
static __device__ __forceinline__ void split_h8(half8 a, short8& ah, short8& al) {
    #pragma unroll
    for (int j = 0; j < 8; ++j) {
        float fv = (float)a[j];
        unsigned u = __float_as_uint(fv);
        float lo = fv - __uint_as_float(u & 0xFFFF0000u);
        ah[j] = (short)(u >> 16);
        al[j] = (short)(__float_as_uint(lo) >> 16);
    }
}

__global__ __launch_bounds__(512, 4) void gemm_kernel(const _Float16* __restrict__ A,
                                                      const unsigned short* __restrict__ Wth,
                                                      const unsigned short* __restrict__ Wtl,
                                                      const float* __restrict__ dinv,
                                                      void* __restrict__ C, int n, int outf) {
    __shared__ unsigned short Wlds[128 * WLDS_STRIDE];
    int tid = threadIdx.x;
    int wave = tid >> 6, lane = tid & 63;
    int m = lane & 15, quad = lane >> 4;
    int row0 = blockIdx.x * 128 + wave * 16;
    int arow = row0 + m; if (arow > n - 1) arow = n - 1;
    size_t n32 = (size_t)n * 32;
    const _Float16* abase = A + (size_t)arow * 32 + quad * 8;

    // prefetch ALL kc A-fragments before W staging (chunk kc holds cols [32kc,32kc+32))
    half8 pa[4];
    #pragma unroll
    for (int kc = 0; kc < 4; ++kc) pa[kc] = *(const half8*)(abase + (size_t)kc * n32);

    stage_w(Wth, Wtl, Wlds, tid);

    floatx4 acc[8];
    #pragma unroll
    for (int ct = 0; ct < 8; ++ct) acc[ct] = (floatx4){0.f, 0.f, 0.f, 0.f};
    __syncthreads();

    #pragma unroll
    for (int kc = 0; kc < 4; ++kc) {
        short8 ah, al;
        split_h8(pa[kc], ah, al);
        #pragma unroll
        for (int ct = 0; ct < 8; ++ct) {
            int base = (ct * 16 + m) * WLDS_STRIDE + kc * 32 + quad * 8;
            short8 wh = *(const short8*)&Wlds[base];
            short8 wl = *(const short8*)&Wlds[base + 128];
            acc[ct] = __builtin_amdgcn_mfma_f32_16x16x32_bf16(ah, wl, acc[ct], 0, 0, 0);
            acc[ct] = __builtin_amdgcn_mfma_f32_16x16x32_bf16(al, wh, acc[ct], 0, 0, 0);
            acc[ct] = __builtin_amdgcn_mfma_f32_16x16x32_bf16(ah, wh, acc[ct], 0, 0, 0);
        }
    }

    float dv[4];
    #pragma unroll
    for (int r = 0; r < 4; ++r) dv[r] = dinv[min(row0 + quad * 4 + r, n - 1)];

    #pragma unroll
    for (int ct = 0; ct < 8; ++ct) {
        #pragma unroll
        for (int r = 0; r < 4; ++r) {
            int row = row0 + quad * 4 + r;
            if (row < n) {
                if (outf) {
                    ((float*)C)[(size_t)row * 128 + ct * 16 + m] = acc[ct][r];
                } else {
                    ((_Float16*)C)[(size_t)(ct >> 1) * n32 + (size_t)row * 32
                                   + (ct & 1) * 16 + m] = (_Float16)(acc[ct][r] * dv[r]);
                }
            }
        }
    }
}

// layer-0 variant: reads fp32 x (row-major input) directly; dinv-scaled fp16-chunked out
__global__ __launch_bounds__(512, 4) void gemm0_kernel(const float* __restrict__ X,
                                                       const unsigned short* __restrict__ Wth,
                                                       const unsigned short* __restrict__ Wtl,
                                                       const float* __restrict__ dinv,
                                                       _Float16* __restrict__ C, int n) {
    __shared__ unsigned short Wlds[128 * WLDS_STRIDE];
    int tid = threadIdx.x;
    int wave = tid >> 6, lane = tid & 63;
    int m = lane & 15, quad = lane >> 4;
    int row0 = blockIdx.x * 128 + wave * 16;
    int arow = row0 + m; if (arow > n - 1) arow = n - 1;
    size_t n32 = (size_t)n * 32;
    const float* aptr = X + (size_t)arow * 128 + quad * 8;

    floatx4 pf0[4], pf1[4];
    #pragma unroll
    for (int kc = 0; kc < 4; ++kc) {
        pf0[kc] = *(const floatx4*)(aptr + kc * 32);
        pf1[kc] = *(const floatx4*)(aptr + kc * 32 + 4);
    }

    stage_w(Wth, Wtl, Wlds, tid);

    floatx4 acc[8];
    #pragma unroll
    for (int ct = 0; ct < 8; ++ct) acc[ct] = (floatx4){0.f, 0.f, 0.f, 0.f};
    __syncthreads();

    #pragma unroll
    for (int kc = 0; kc < 4; ++kc) {
        short8 ah, al;
        #pragma unroll
        for (int j = 0; j < 8; ++j) {
            float fv = (j < 4) ? pf0[kc][j] : pf1[kc][j - 4];
            unsigned short h = f2bf(fv);
            ah[j] = (short)h;
            al[j] = (short)f2bf(fv - bf2f(h));
        }
        #pragma unroll
        for (int ct = 0; ct < 8; ++ct) {
            int base = (ct * 16 + m) * WLDS_STRIDE + kc * 32 + quad * 8;
            short8 wh = *(const short8*)&Wlds[base];
            short8 wl = *(const short8*)&Wlds[base + 128];
            acc[ct] = __builtin_amdgcn_mfma_f32_16x16x32_bf16(ah, wl, acc[ct], 0, 0, 0);
            acc[ct] = __builtin_amdgcn_mfma_f32_16x16x32_bf16(al, wh, acc[ct], 0, 0, 0);
            acc[ct] = __builtin_amdgcn_mfma_f32_16x16x32_bf16(ah, wh, acc[ct], 0, 0, 0);
        }
    }

    float dv[4];
    #pragma unroll
    for (int r = 0; r < 4; ++r) dv[r] = dinv[min(row0 + quad * 4 + r, n - 1)];

    #pragma unroll
    for (int ct = 0; ct < 8; ++ct) {
        #pragma unroll
        for (int r = 0; r < 4; ++r) {
            int row = row0 + quad * 4 + r;
            if (row < n)
                C[(size_t)(ct >> 1) * n32 + (size_t)row * 32 + (ct & 1) * 16 + m] =
                    (_Float16)(acc[ct][r] * dv[r]);
        }
    }
}

// ---------------- aggregation: fp16 in, fp16 out, weight-free csr, XCD-pinned ----------
// tA layout: [4][node][32] fp16 (dinv-prescaled). blockIdx%8 = s: chunk=s&3, half=s>>2.
// out h[c] = relu( dinv[c] * (tA[c] + sum_{r in N(c)} tA[r]) + bias ), stored fp16
// in the SAME chunk4 layout (tB) -> next gemm reads it directly.

__global__ __launch_bounds__(256) void agg_kernel(const _Float16* __restrict__ t,
                                                  const float* __restrict__ bias,
                                                  const int* __restrict__ rp,
                                                  const int* __restrict__ csr,
                                                  const float* __restrict__ dinv,
                                                  _Float16* __restrict__ outp, int n, int nh) {
    int s = blockIdx.x & 7;
    int chunk = s & 3;
    int half = s >> 2;
    int nb = blockIdx.x >> 3;
    int group = threadIdx.x >> 2;          // 64 nodes per block
    int lane4 = threadIdx.x & 3;
    int j = half * nh + nb * 64 + group;
    int jend = half ? n : nh;
    if (j >= jend) return;
    size_t n32 = (size_t)n * 32;
    const _Float16* tc = t + (size_t)chunk * n32;
    int c8 = lane4 * 8;                    // col offset within the 32-col chunk
    int p0 = rp[j], p1 = rp[j + 1];

    // self-loop term = tA[j] (weight folded): coalesced read, issued first
    float dj = dinv[j];
    half8 vs = *(const half8*)&tc[(size_t)j * 32 + c8];

    float acc[8];
    #pragma unroll
    for (int k = 0; k < 8; ++k) acc[k] = (float)vs[k];

    int p = p0;
    for (; p + 8 <= p1; p += 8) {
        int e[8];
        #pragma unroll
        for (int i = 0; i < 8; ++i) e[i] = csr[p + i];
        half8 v[8];
        #pragma unroll
        for (int i = 0; i < 8; ++i)
            v[i] = *(const half8*)&tc[(size_t)e[i] * 32 + c8];
        #pragma unroll
        for (int i = 0; i < 8; ++i) {
            #pragma unroll
            for (int k = 0; k < 8; ++k) acc[k] += (float)v[i][k];
        }
    }
    if (p < p1) {
        int lim = p1 - 1;
        int e[8];
        #pragma unroll
        for (int i = 0; i < 8; ++i) e[i] = csr[min(p + i, lim)];
        float msk[8];
        #pragma unroll
        for (int i = 0; i < 8; ++i) msk[i] = (p + i < p1) ? 1.f : 0.f;
        half8 v[8];
        #pragma unroll
        for (int i = 0; i < 8; ++i)
            v[i] = *(const half8*)&tc[(size_t)e[i] * 32 + c8];
        #pragma unroll
        for (int i = 0; i < 8; ++i) {
            #pragma unroll
            for (int k = 0; k < 8; ++k) acc[k] += msk[i] * (float)v[i][k];
        }
    }

    int cbase = chunk * 32 + c8;
    float4 b0 = *(const float4*)&bias[cbase];
    float4 b1 = *(const float4*)&bias[cbase + 4];
    float bb[8] = {b0.x, b0.y, b0.z, b0.w, b1.x, b1.y, b1.z, b1.w};
    half8 hv;
    #pragma unroll
    for (int k = 0; k < 8; ++k) hv[k] = (_Float16)fmaxf(fmaf(dj, acc[k], bb[k]), 0.f);

    *(half8*)&outp[(size_t)chunk * n32 + (size_t)j * 32 + c8] = hv;
}

// ---------------- pooling + classifier (row-major fp32 final activations) ----------------

__global__ __launch_bounds__(256) void pool_kernel(const float* __restrict__ t,
                                                   const float* __restrict__ bfc,
                                                   const int* __restrict__ batch,
                                                   const float* __restrict__ Wlin,
                                                   const float* __restrict__ blin,
                                                   float* __restrict__ out, int n) {
    int g = blockIdx.x;
    int tid = threadIdx.x;
    int lo = 0, hi = n;
    while (lo < hi) { int m = (lo + hi) >> 1; if (batch[m] < g) lo = m + 1; else hi = m; }
    int start = lo;
    lo = start; hi = n;
    while (lo < hi) { int m = (lo + hi) >> 1; if (batch[m] < g + 1) lo = m + 1; else hi = m; }
    int end = lo;

    int lane = tid & 31, sub = tid >> 5;
    int c4 = lane * 4;
    float4 bv = *(const float4*)&bfc[c4];
    float sx = 0.f, sy = 0.f, sz = 0.f, sw = 0.f;
    for (int j = start + sub; j < end; j += 8) {
        float4 v = *(const float4*)&t[(size_t)j * 128 + c4];
        sx += fmaxf(v.x + bv.x, 0.f);
        sy += fmaxf(v.y + bv.y, 0.f);
        sz += fmaxf(v.z + bv.z, 0.f);
        sw += fmaxf(v.w + bv.w, 0.f);
    }
    __shared__ float red[8][128];
    red[sub][c4] = sx; red[sub][c4 + 1] = sy; red[sub][c4 + 2] = sz; red[sub][c4 + 3] = sw;
    __syncthreads();
    __shared__ float pooled[128];
    if (tid < 128) {
        float s = 0.f;
        #pragma unroll
        for (int k = 0; k < 8; ++k) s += red[k][tid];
        float pv = s / fmaxf((float)(end - start), 1.f);
        pooled[tid] = pv;
        out[1280 + g * 128 + tid] = pv;
    }
    __syncthreads();
    if (tid < 10) {
        float a = blin[tid];
        for (int k = 0; k < 128; ++k) a += pooled[k] * Wlin[k * 10 + tid];
        out[g * 10 + tid] = a;
    }
}

// ---------------- launch ----------------

extern "C" void kernel_launch(void* const* d_in, const int* in_sizes, int n_in,
                              void* d_out, int out_size, void* d_ws, size_t ws_size,
                              hipStream_t stream) {
    const float* x     = (const float*)d_in[0];
    const int*   ei    = (const int*)d_in[1];
    const int*   batch = (const int*)d_in[2];
    const float* Wl[6] = {(const float*)d_in[3], (const float*)d_in[5], (const float*)d_in[7],
                          (const float*)d_in[9], (const float*)d_in[11], (const float*)d_in[13]};
    const float* bl[6] = {(const float*)d_in[4], (const float*)d_in[6], (const float*)d_in[8],
                          (const float*)d_in[10], (const float*)d_in[12], (const float*)d_in[14]};
    const float* Wlin = (const float*)d_in[15];
    const float* blin = (const float*)d_in[16];

    const int N = in_sizes[2];        // 50000
    const int E = in_sizes[1] / 2;    // 600000
    (void)n_in; (void)out_size; (void)ws_size;

    char* p = (char*)d_ws;
    auto carve = [&](size_t bytes) { void* r = (void*)p; p += (bytes + 255) & ~(size_t)255; return r; };
    _Float16*       tA     = (_Float16*)carve((size_t)N * 128 * 2);   // gemm out (dinv-scaled)
    _Float16*       tB     = (_Float16*)carve((size_t)N * 128 * 2);   // agg out (h)
    float*          tf     = (float*)carve((size_t)N * 128 * 4);      // final fp32 activations
    int*            degi   = (int*)carve((size_t)N * 4);
    float*          dinv   = (float*)carve((size_t)N * 4);
    int*            rp     = (int*)carve((size_t)(N + 1) * 4);
    int*            cursor = (int*)carve((size_t)N * 4);
    int*            csr    = (int*)carve((size_t)E * 4);              // 4B source index only
    int*            bsum   = (int*)carve(256 * 4);
    unsigned short* wth    = (unsigned short*)carve(6 * 16384 * 2);
    unsigned short* wtl    = (unsigned short*)carve(6 * 16384 * 2);

    int gN = (N + 255) / 256;
    int gCount = (E + 255) / 256;
    hipMemsetAsync(degi, 0, (size_t)N * 4, stream);
    count_packw_kernel<<<gCount + 384, 256, 0, stream>>>(ei, degi, E, gCount,
                                                         Wl[0], Wl[1], Wl[2], Wl[3], Wl[4],
                                                         Wl[5], wth, wtl);
    scan_bsum_kernel<<<gN, 256, 0, stream>>>(degi, dinv, bsum, N);
    scan_emit_kernel<<<gN, 256, 0, stream>>>(degi, bsum, rp, cursor, N, gN);
    fill_kernel<<<gCount, 256, 0, stream>>>(ei, cursor, csr, E);

    int NH = (N + 1) / 2;
    int gGemm = (N + 127) / 128;
    int gAgg  = 8 * ((NH + 63) / 64);   // s = bid%8: chunk = s&3, node-half = s>>2
    gemm0_kernel<<<gGemm, 512, 0, stream>>>(x, wth, wtl, dinv, tA, N);
    agg_kernel<<<gAgg, 256, 0, stream>>>(tA, bl[0], rp, csr, dinv, tB, N, NH);
    for (int l = 1; l < 5; ++l) {
        gemm_kernel<<<gGemm, 512, 0, stream>>>(tB, wth + l * 16384, wtl + l * 16384,
                                               dinv, (void*)tA, N, 0);
        agg_kernel<<<gAgg, 256, 0, stream>>>(tA, bl[l], rp, csr, dinv, tB, N, NH);
    }
    gemm_kernel<<<gGemm, 512, 0, stream>>>(tB, wth + 5 * 16384, wtl + 5 * 16384,
                                           dinv, (void*)tf, N, 1);
    pool_kernel<<<128, 256, 0, stream>>>(tf, bl[5], batch, Wlin, blin, (float*)d_out, N);
}